// Round 3
// baseline (602.869 us; speedup 1.0000x reference)
//
#include <hip/hip_runtime.h>

#define N_NODES 100000
#define N_EDGES 3200000
#define F_IN 512
#define F_OUT 256
#define BK 32
#define NK (F_IN / BK)   // 16

typedef short bf16x8 __attribute__((ext_vector_type(8)));
typedef short bf16x4 __attribute__((ext_vector_type(4)));
typedef float f32x4 __attribute__((ext_vector_type(4)));
typedef unsigned u32x4 __attribute__((ext_vector_type(4)));

__device__ __forceinline__ short f2b(float f) {
    unsigned u = __builtin_bit_cast(unsigned, f);
    u += 0x7fffu + ((u >> 16) & 1u);   // round-to-nearest-even
    return (short)(u >> 16);
}
__device__ __forceinline__ float b2f(short s) {
    unsigned u = ((unsigned)(unsigned short)s) << 16;
    return __builtin_bit_cast(float, u);
}
// pack two fp32 -> two bf16 (round-half-up): 2 adds + 1 v_perm
__device__ __forceinline__ unsigned pack2(float f0, float f1) {
    unsigned u0 = __builtin_bit_cast(unsigned, f0) + 0x8000u;
    unsigned u1 = __builtin_bit_cast(unsigned, f1) + 0x8000u;
    return __builtin_amdgcn_perm(u1, u0, 0x07060302);  // [u0.hi16, u1.hi16]
}

// --- Kernel 0a: W [512][256] fp32 -> Wt [256][512] bf16 (transposed) ---
__global__ void k_wconv(const float* __restrict__ W, short* __restrict__ Wt) {
    int idx = blockIdx.x * 256 + threadIdx.x;
    int k = idx >> 8;
    int n = idx & 255;
    Wt[n * F_IN + k] = f2b(W[idx]);
}

// --- Kernel 0b: row_ptr via lower_bound on sorted edge_row ---
__global__ void k_rowptr(const int* __restrict__ erow, int* __restrict__ rp) {
    int i = blockIdx.x * 256 + threadIdx.x;
    if (i > N_NODES) return;
    int lo = 0, hi = N_EDGES;
    while (lo < hi) {
        int mid = (lo + hi) >> 1;
        if (erow[mid] < i) lo = mid + 1; else hi = mid;
    }
    rp[i] = lo;
}

// --- Kernel 1: S = x @ W (bf16 MFMA). 128x256 tile, 8 waves (2x4), wave 64x64.
// A staged as bf16 through VGPRs (cvt once), double-buffered LDS, depth-2
// register prefetch so HBM latency never hits a barrier drain.
__global__ __launch_bounds__(512, 4) void k_gemm(const float* __restrict__ X,
                                                 const short* __restrict__ Wt,
                                                 short* __restrict__ S) {
    __shared__ __align__(16) short As[2][128 * 40];   // 80 B row stride, 20 KB
    const int tid  = threadIdx.x;
    const int wave = tid >> 6;
    const int lane = tid & 63;
    const int wr   = wave >> 2;        // 0..1 row group
    const int wc   = wave & 3;         // 0..3 col group
    const int l15  = lane & 15, quad = lane >> 4;
    const long row_base = (long)blockIdx.x * 128;

    f32x4 acc[4][4];
#pragma unroll
    for (int i = 0; i < 4; ++i)
#pragma unroll
        for (int j = 0; j < 4; ++j) acc[i][j] = (f32x4){0.f, 0.f, 0.f, 0.f};

    // staging: thread t owns row t>>2, cols (t&3)*8 .. +8
    const int srow = tid >> 2;
    const int scol = (tid & 3) * 8;
    long grow = row_base + srow;
    if (grow >= N_NODES) grow = N_NODES - 1;   // clamp; masked at epilogue
    const float* gp = X + grow * F_IN + scol;
    short* wp = &As[0][srow * 40 + scol];

    const short* wtb = Wt + (wc * 64 + l15) * F_IN + quad * 8;
    const short* arp = &As[0][(wr * 64 + l15) * 40 + quad * 8];

    // prologue: regs slot0 <- k0=0, slot1 <- k0=1; LDS buf0 <- k0=0
    f32x4 rlo[2], rhi[2];
    rlo[0] = *(const f32x4*)(gp);
    rhi[0] = *(const f32x4*)(gp + 4);
    rlo[1] = *(const f32x4*)(gp + BK);
    rhi[1] = *(const f32x4*)(gp + BK + 4);
    {
        u32x4 pv = { pack2(rlo[0].x, rlo[0].y), pack2(rlo[0].z, rlo[0].w),
                     pack2(rhi[0].x, rhi[0].y), pack2(rhi[0].z, rhi[0].w) };
        *(u32x4*)wp = pv;
    }

#pragma unroll
    for (int k0 = 0; k0 < NK; ++k0) {
        const int cur = k0 & 1;
        // prefetch A for k0+2 into freed slot (in flight across this whole iter)
        if (k0 + 2 < NK) {
            rlo[cur] = *(const f32x4*)(gp + (k0 + 2) * BK);
            rhi[cur] = *(const f32x4*)(gp + (k0 + 2) * BK + 4);
        }
        bf16x8 bfrag[4];
#pragma unroll
        for (int j = 0; j < 4; ++j)
            bfrag[j] = *(const bf16x8*)(wtb + j * 16 * F_IN + k0 * BK);

        __syncthreads();   // buf[cur] writes visible; prev-iter reads of buf[cur^1] done

        bf16x8 afrag[4];
#pragma unroll
        for (int i = 0; i < 4; ++i)
            afrag[i] = *(const bf16x8*)(arp + cur * (128 * 40) + i * 16 * 40);
#pragma unroll
        for (int i = 0; i < 4; ++i)
#pragma unroll
            for (int j = 0; j < 4; ++j)
                acc[i][j] = __builtin_amdgcn_mfma_f32_16x16x32_bf16(
                    afrag[i], bfrag[j], acc[i][j], 0, 0, 0);

        // write k0+1 (loaded 1.5 iters ago -> latency hidden) into other buffer
        if (k0 + 1 < NK) {
            const int nxt = cur ^ 1;
            u32x4 pv = { pack2(rlo[nxt].x, rlo[nxt].y), pack2(rlo[nxt].z, rlo[nxt].w),
                         pack2(rhi[nxt].x, rhi[nxt].y), pack2(rhi[nxt].z, rhi[nxt].w) };
            *(u32x4*)(wp + nxt * (128 * 40)) = pv;
        }
    }

    // epilogue: C/D layout col=lane&15, row=quad*4+reg
#pragma unroll
    for (int i = 0; i < 4; ++i) {
#pragma unroll
        for (int rg = 0; rg < 4; ++rg) {
            long gm = row_base + wr * 64 + i * 16 + quad * 4 + rg;
            if (gm < N_NODES) {
#pragma unroll
                for (int j = 0; j < 4; ++j) {
                    int gn = wc * 64 + j * 16 + l15;
                    S[gm * F_OUT + gn] = f2b(acc[i][j][rg]);
                }
            }
        }
    }
}

// --- Kernel 2: out = spmm(adj, S). 2 rows/wave (one per half-wave), lane owns
// 8 cols (16B gathers), depth-4 software pipeline (4 gathers in flight).
__global__ __launch_bounds__(256) void k_spmm(const short* __restrict__ S,
                                              const int* __restrict__ ecol,
                                              const float* __restrict__ ev,
                                              const int* __restrict__ rp,
                                              float* __restrict__ out) {
    const int wave = threadIdx.x >> 6, lane = threadIdx.x & 63;
    const int half = lane >> 5, hl = lane & 31;
    const int r = (blockIdx.x * 4 + wave) * 2 + half;   // grid 12500 -> r < 100000
    const int lo = rp[r], hi = rp[r + 1];
    const short* sp = S + hl * 8;
    float a[8] = {0.f, 0.f, 0.f, 0.f, 0.f, 0.f, 0.f, 0.f};
    if (lo < hi) {
        const int him1 = hi - 1;
        float v[4]; bf16x8 s[4];
#define FETCH(E, J) { int _e = (E); int _ee = _e < him1 ? _e : him1;            \
                      float _vt = ev[_ee];                                      \
                      v[J] = (_e < hi) ? _vt : 0.f;                             \
                      s[J] = *(const bf16x8*)(sp + (long)ecol[_ee] * F_OUT); }
        FETCH(lo + 0, 0); FETCH(lo + 1, 1); FETCH(lo + 2, 2); FETCH(lo + 3, 3);
        for (int base = lo; base < hi; base += 4) {
            float cv0 = v[0], cv1 = v[1], cv2 = v[2], cv3 = v[3];
            bf16x8 cs0 = s[0], cs1 = s[1], cs2 = s[2], cs3 = s[3];
            FETCH(base + 4, 0); FETCH(base + 5, 1);
            FETCH(base + 6, 2); FETCH(base + 7, 3);
#pragma unroll
            for (int i = 0; i < 8; ++i) {
                a[i] += cv0 * b2f(cs0[i]);
                a[i] += cv1 * b2f(cs1[i]);
                a[i] += cv2 * b2f(cs2[i]);
                a[i] += cv3 * b2f(cs3[i]);
            }
        }
#undef FETCH
    }
    f32x4 o0 = {a[0], a[1], a[2], a[3]};
    f32x4 o1 = {a[4], a[5], a[6], a[7]};
    float* op = out + (long)r * F_OUT + hl * 8;
    *(f32x4*)op = o0;
    *(f32x4*)(op + 4) = o1;
}

extern "C" void kernel_launch(void* const* d_in, const int* in_sizes, int n_in,
                              void* d_out, int out_size, void* d_ws, size_t ws_size,
                              hipStream_t stream) {
    const float* x    = (const float*)d_in[0];
    const float* w    = (const float*)d_in[1];
    const int*   erow = (const int*)d_in[2];
    const int*   ecol = (const int*)d_in[3];
    const float* ev   = (const float*)d_in[4];
    float* out = (float*)d_out;

    // ws layout: [0,262144) Wt bf16 | [262144,662148) row_ptr | [1MiB,+51.2MB) S bf16
    char* ws = (char*)d_ws;
    short* Wt = (short*)ws;
    int*   rp = (int*)(ws + 262144);
    short* S  = (short*)(ws + (1 << 20));

    k_wconv<<<512, 256, 0, stream>>>(w, Wt);
    k_rowptr<<<(N_NODES + 256) / 256, 256, 0, stream>>>(erow, rp);
    k_gemm<<<(N_NODES + 127) / 128, 512, 0, stream>>>(x, Wt, S);
    k_spmm<<<N_NODES / 8, 256, 0, stream>>>(S, ecol, ev, rp, out);
}